// Round 3
// baseline (612.071 us; speedup 1.0000x reference)
//
#include <hip/hip_runtime.h>

#define B_ 32
#define C_ 128
#define HW_ 128
#define CIN_ 64
#define COUT_ 128
#define SPATIAL (HW_ * HW_)  // 16384

typedef unsigned short u16;
typedef unsigned int u32;
typedef short s16x8 __attribute__((ext_vector_type(8)));   // 8 bf16 (4 VGPRs)
typedef float f32x16 __attribute__((ext_vector_type(16))); // 32x32 MFMA acc

// Split fp32 -> bf16 hi + bf16 lo (RNE both). x ~= hi + lo with ~2^-17 rel error.
__device__ __forceinline__ void split_bf16(float x, u16& hi, u16& lo) {
    u32 u = __float_as_uint(x);
    u32 rh = (u + 0x7FFFu + ((u >> 16) & 1u)) >> 16;
    float hf = __uint_as_float(rh << 16);
    float r = x - hf;
    u32 v = __float_as_uint(r);
    u32 rl = (v + 0x7FFFu + ((v >> 16) & 1u)) >> 16;
    hi = (u16)rh; lo = (u16)rl;
}

// Single RNE round fp32 -> bf16.
__device__ __forceinline__ u16 rnd_bf16(float x) {
    u32 u = __float_as_uint(x);
    return (u16)((u + 0x7FFFu + ((u >> 16) & 1u)) >> 16);
}

__device__ __forceinline__ u32 pack2(float a, float b) {
    return (u32)rnd_bf16(a) | ((u32)rnd_bf16(b) << 16);
}

// ---------------------------------------------------------------------------
// Kernel 1: per-(b,c) spatial sum, double accumulation (unchanged).
// ---------------------------------------------------------------------------
__global__ __launch_bounds__(256) void k_chansum(const float* __restrict__ x,
                                                 double* __restrict__ sums) {
    int bc = blockIdx.x;
    const float4* p4 = (const float4*)(x + (size_t)bc * SPATIAL);
    int t = threadIdx.x;
    double s = 0.0;
#pragma unroll
    for (int i = 0; i < 16; ++i) {
        float4 v = p4[t + 256 * i];
        s += (double)v.x + (double)v.y + (double)v.z + (double)v.w;
    }
#pragma unroll
    for (int off = 32; off > 0; off >>= 1) s += __shfl_down(s, off, 64);
    __shared__ double wsum[4];
    if ((t & 63) == 0) wsum[t >> 6] = s;
    __syncthreads();
    if (t == 0) sums[bc] = wsum[0] + wsum[1] + wsum[2] + wsum[3];
}

// ---------------------------------------------------------------------------
// Kernel 2: stable argsort-by-rank, keep first CIN_ ranks (unchanged).
// ---------------------------------------------------------------------------
__global__ __launch_bounds__(128) void k_select(const double* __restrict__ sums,
                                                int* __restrict__ idx) {
    int b = blockIdx.x, c = threadIdx.x;
    __shared__ double s[C_];
    double my = sums[b * C_ + c];
    s[c] = my;
    __syncthreads();
    int rank = 0;
    for (int j = 0; j < C_; ++j) {
        double v = s[j];
        rank += (v < my || (v == my && j < c)) ? 1 : 0;
    }
    if (rank < CIN_) idx[b * CIN_ + rank] = c;
}

// ---------------------------------------------------------------------------
// Kernel 3: weight prep — scatter w[Cout][Cin][3][3] f32 into A-fragment order
// for v_mfma_f32_32x32x16_bf16, hi and lo bf16 planes (w exact to 2^-17).
// Layout: wf[(((hl*9 + tap)*4 + ks)*4 + cot)*512 + lane*8 + e]
//   co = cot*32 + (lane&31); ci = ks*16 + (lane>>5)*8 + e.  288 KB, L2-hot.
// ---------------------------------------------------------------------------
__global__ __launch_bounds__(256) void k_wprep(const float* __restrict__ w,
                                               u16* __restrict__ wf) {
    int bid = blockIdx.x;            // 0..287 = hl*144 + tap*16 + ks*4 + cot
    int hl = bid / 144, rem = bid % 144;
    int tap = rem / 16, r2 = rem % 16;
    int ks = r2 / 4, cot = r2 % 4;
    int dh = tap / 3, dw = tap % 3;
    for (int j = threadIdx.x; j < 512; j += 256) {
        int lane = j >> 3, e = j & 7;
        int co = cot * 32 + (lane & 31);
        int ci = ks * 16 + (lane >> 5) * 8 + e;
        float v = w[((co * CIN_ + ci) * 3 + dh) * 3 + dw];
        u16 h, l; split_bf16(v, h, l);
        wf[(size_t)bid * 512 + j] = hl ? l : h;
    }
}

// ---------------------------------------------------------------------------
// Kernel 4: implicit-GEMM conv via bf16 MFMA, 2-pass (w = wh + wl exact,
// x single bf16 plane). PIPELINED: ci split into 4 quarters of 16,
// double-buffered LDS tile [2][10r][34w][16ci] (21.25 KB + sidx).
// Per quarter: issue next quarter's gather loads into regs BEFORE the
// 144-MFMA compute phase; convert + ds_write after the barrier (T14).
// Swizzle: 16B slot stored at s ^ ((w>>2)&1); read slot = lk ^ ((wT>>2)&1)
// -> each 16-lane b128 phase covers all 8 bank-quads at 2 lanes/quad (min).
// s_setprio(1) around MFMA clusters (T5; phase role-split now exists).
// ---------------------------------------------------------------------------
#define ROWS 8
#define WC 32
#define TSZ (10 * 34 * 16)   // 5440 u16 per buffer
#define UNITS (2 * 10 * 34)  // 680 stage units of 8 ci each

__global__ __launch_bounds__(256, 2) void k_conv_mfma(
    const float* __restrict__ x, const u16* __restrict__ wf,
    const float* __restrict__ bias, const int* __restrict__ idx,
    float* __restrict__ out)
{
    __shared__ __align__(16) u16 tile[2][TSZ];
    __shared__ int sidx[CIN_];

    const int b = blockIdx.z;
    const int h0 = blockIdx.y * ROWS;
    const int w0 = blockIdx.x * WC;
    const int t = threadIdx.x;
    const int lane = t & 63;
    const int wv = t >> 6;
    const int g  = wv & 1;      // co0 = g*64
    const int rg = wv >> 1;     // rows rg*4 .. rg*4+3
    const int lc = lane & 31;   // MFMA col (w position)
    const int lk = lane >> 5;   // k-group select

    if (t < CIN_) sidx[t] = idx[b * CIN_ + t];

    // acc init with bias; C/D map: col=lane&31, row=(q&3)+8*(q>>2)+4*(lane>>5)
    f32x16 acc[2][4];
#pragma unroll
    for (int ct = 0; ct < 2; ++ct)
#pragma unroll
        for (int q = 0; q < 16; ++q) {
            int row = (q & 3) + 8 * (q >> 2) + 4 * lk;
            float bv = bias[g * 64 + ct * 32 + row];
#pragma unroll
            for (int rr = 0; rr < 4; ++rr) acc[ct][rr][q] = bv;
        }

    const float* xb = x + ((size_t)b << 21);  // b * C_ * SPATIAL

    float pre[3][8];  // in-flight gather for next quarter (24 VGPR)

    // issue: start global gather loads for quarter qq into pre[][]
    auto issue = [&](int qq) {
#pragma unroll
        for (int u = 0; u < 3; ++u) {
            int e = t + 256 * u;
            bool ve = (e < UNITS);
            int w_  = e % 34;
            int tmp = e / 34;      // <= 19 when ve
            int r   = tmp % 10;
            int s   = tmp / 10;    // 0/1 -> ci sub-group of 8
            int gh = h0 + r - 1, gw = w0 + w_ - 1;
            bool ok = ve && ((unsigned)gh < (unsigned)HW_) && ((unsigned)gw < (unsigned)HW_);
            int off = (gh << 7) + gw;
            int cb = qq * 16 + s * 8;
#pragma unroll
            for (int i = 0; i < 8; ++i) {
                float v = 0.f;
                if (ok) v = xb[((size_t)sidx[cb + i] << 14) + off];
                pre[u][i] = v;
            }
        }
    };

    // commit: convert pre -> bf16, ds_write into tile[buf] (swizzled)
    auto commit = [&](int buf) {
#pragma unroll
        for (int u = 0; u < 3; ++u) {
            int e = t + 256 * u;
            if (e < UNITS) {
                int w_  = e % 34;
                int tmp = e / 34;
                int r   = tmp % 10;
                int s   = tmp / 10;
                uint4 ph;
                ph.x = pack2(pre[u][0], pre[u][1]);
                ph.y = pack2(pre[u][2], pre[u][3]);
                ph.z = pack2(pre[u][4], pre[u][5]);
                ph.w = pack2(pre[u][6], pre[u][7]);
                int slot = s ^ ((w_ >> 2) & 1);
                int si = (r * 34 + w_) * 16 + slot * 8;  // u16 idx, 16B aligned
                *(uint4*)&tile[buf][si] = ph;
            }
        }
    };

    // compute: 9 taps x (4 B-frag ds_read_b128 + 4 A-frag L2 loads + 16 MFMA)
    auto compute = [&](int qq, int buf) {
#pragma unroll
        for (int dh = 0; dh < 3; ++dh) {
#pragma unroll
            for (int dw = 0; dw < 3; ++dw) {
                const int tap = dh * 3 + dw;
                int wT = lc + dw;                        // 0..33
                int sr = (lk ^ ((wT >> 2) & 1)) * 8;
                uint4 bh[4];
#pragma unroll
                for (int rr = 0; rr < 4; ++rr) {
                    int a = ((rg * 4 + dh + rr) * 34 + wT) * 16 + sr;
                    bh[rr] = *(const uint4*)&tile[buf][a];
                }
                const u16* pH = wf + ((size_t)(((0 * 9 + tap) * 4 + qq) * 4 + g * 2) << 9) + lane * 8;
                const u16* pL = wf + ((size_t)(((1 * 9 + tap) * 4 + qq) * 4 + g * 2) << 9) + lane * 8;
                __builtin_amdgcn_s_setprio(1);
#pragma unroll
                for (int ct = 0; ct < 2; ++ct) {
                    s16x8 ah = *(const s16x8*)(pH + ct * 512);
                    s16x8 al = *(const s16x8*)(pL + ct * 512);
#pragma unroll
                    for (int rr = 0; rr < 4; ++rr) {
                        s16x8 bv = __builtin_bit_cast(s16x8, bh[rr]);
                        acc[ct][rr] = __builtin_amdgcn_mfma_f32_32x32x16_bf16(ah, bv, acc[ct][rr], 0, 0, 0);
                        acc[ct][rr] = __builtin_amdgcn_mfma_f32_32x32x16_bf16(al, bv, acc[ct][rr], 0, 0, 0);
                    }
                }
                __builtin_amdgcn_s_setprio(0);
            }
        }
    };

    __syncthreads();            // sidx visible
    issue(0);
    commit(0);                  // prologue: only exposed stage latency
    __syncthreads();

#pragma unroll 1
    for (int qq = 0; qq < 4; ++qq) {
        if (qq < 3) issue(qq + 1);          // loads fly during compute
        compute(qq, qq & 1);
        __syncthreads();                    // all waves done reading tile[qq&1]
        if (qq < 3) {
            commit((qq + 1) & 1);           // vmcnt wait lands here (hidden)
            __syncthreads();
        }
    }

    // epilogue: D col=lane&31 -> w, row -> co; rr -> h row
    const int orow0 = h0 + rg * 4;
    size_t ob = (((size_t)(b * COUT_ + g * 64)) << 14) + ((size_t)orow0 << 7) + w0 + lc;
#pragma unroll
    for (int ct = 0; ct < 2; ++ct)
#pragma unroll
        for (int rr = 0; rr < 4; ++rr)
#pragma unroll
            for (int q = 0; q < 16; ++q) {
                int row = (q & 3) + 8 * (q >> 2) + 4 * lk;
                out[ob + (((size_t)(ct * 32 + row)) << 14) + ((size_t)rr << 7)] = acc[ct][rr][q];
            }
}

// ---------------------------------------------------------------------------
// Workspace: sums 32768 B @0, idx 8192 B @32768, wfrag 294912 B @40960
// (total ~328 KB).
// ---------------------------------------------------------------------------
extern "C" void kernel_launch(void* const* d_in, const int* in_sizes, int n_in,
                              void* d_out, int out_size, void* d_ws, size_t ws_size,
                              hipStream_t stream) {
    const float* x    = (const float*)d_in[0];
    const float* w    = (const float*)d_in[1];
    const float* bias = (const float*)d_in[2];
    float* out = (float*)d_out;

    double* sums = (double*)d_ws;
    int* idx     = (int*)((char*)d_ws + 32768);
    u16* wfrag   = (u16*)((char*)d_ws + 40960);

    k_chansum<<<B_ * C_, 256, 0, stream>>>(x, sums);
    k_select<<<B_, 128, 0, stream>>>(sums, idx);
    k_wprep<<<288, 256, 0, stream>>>(w, wfrag);

    dim3 grid(HW_ / WC, HW_ / ROWS, B_);  // (4, 16, 32) = 2048 blocks
    k_conv_mfma<<<grid, 256, 0, stream>>>(x, wfrag, bias, idx, out);
}